// Round 13
// baseline (98.503 us; speedup 1.0000x reference)
//
#include <hip/hip_runtime.h>
#include <cstddef>

#define NCAPS  10
#define BATCH  256
#define NROUTE 1152
#define CIN    8
#define COUT   16
#define T      768           // 12 waves; LDS ~74.8KB -> 2 blocks/CU = 24 waves/CU
#define NB     2             // batch elements per block
#define NWAVE  (T / 64)
#define NBLK   (NCAPS * (BATCH / NB))   // 1280 blocks = 5 per CU
#define PLANE  (NROUTE * 8)             // u32 (bf16x2) per b-plane = 9216
#define XPLANE (NROUTE * CIN)           // floats per x b-plane = 9216
#define LOG2E  1.4426950408889634f

// bijective 16B-unit swizzle (validated rounds 5-12): conflict-minimal ds_read
__device__ __forceinline__ unsigned swzu(unsigned unit) { return unit ^ ((unit >> 3) & 3u); }

// pack two fp32 -> bf16x2 (RNE), low16 = a
__device__ __forceinline__ unsigned pack_bf16(float a, float b) {
    unsigned ua = __float_as_uint(a); ua += 0x7fffu + ((ua >> 16) & 1u);
    unsigned ub = __float_as_uint(b); ub += 0x7fffu + ((ub >> 16) & 1u);
    return (ua >> 16) | (ub & 0xffff0000u);
}
__device__ __forceinline__ float blo(unsigned u) { return __uint_as_float(u << 16); }
__device__ __forceinline__ float bhi(unsigned u) { return __uint_as_float(u & 0xffff0000u); }

__device__ __forceinline__ float wave_sum(float v) {
    v += __shfl_xor(v, 1);  v += __shfl_xor(v, 2);  v += __shfl_xor(v, 4);
    v += __shfl_xor(v, 8);  v += __shfl_xor(v, 16); v += __shfl_xor(v, 32);
    return v;
}

// Component-splitting butterfly: reduces s[0..15] over 64 lanes. Lane L (L<16)
// ends with the wave total of comp(L)=((L&1)<<3)|((L&2)<<1)|((L&4)>>1)|((L&8)>>3).
__device__ __forceinline__ float wave_sum16(float* s, int lane) {
#pragma unroll
    for (int j = 0; j < 8; ++j) {
        float snd = (lane & 1) ? s[j] : s[j + 8];
        float r = __shfl_xor(snd, 1);
        s[j] = ((lane & 1) ? s[j + 8] : s[j]) + r;
    }
#pragma unroll
    for (int j = 0; j < 4; ++j) {
        float snd = (lane & 2) ? s[j] : s[j + 4];
        float r = __shfl_xor(snd, 2);
        s[j] = ((lane & 2) ? s[j + 4] : s[j]) + r;
    }
#pragma unroll
    for (int j = 0; j < 2; ++j) {
        float snd = (lane & 4) ? s[j] : s[j + 2];
        float r = __shfl_xor(snd, 4);
        s[j] = ((lane & 4) ? s[j + 2] : s[j]) + r;
    }
    {
        float snd = (lane & 8) ? s[0] : s[1];
        float r = __shfl_xor(snd, 8);
        s[0] = ((lane & 8) ? s[1] : s[0]) + r;
    }
    s[0] += __shfl_xor(s[0], 16);
    s[0] += __shfl_xor(s[0], 32);
    return s[0];
}

union U4 { uint4 v; unsigned u[4]; };

// Phase-A unit (validated shape, NB=2): unit u -> route r=u>>3, out-pair j=u&7.
__device__ __forceinline__ void phaseA_unit(int u, const float* __restrict__ Wc,
                                            const float* __restrict__ xb,
                                            unsigned* prLDS) {
    const int r = u >> 3;
    const int j = u & 7;
    float xs[NB][CIN];
#pragma unroll
    for (int b = 0; b < NB; ++b) {
        const float4* xq = (const float4*)(xb + (size_t)b * XPLANE + r * CIN);
        float4 xa = xq[0], xv = xq[1];      // 8-lane broadcast
        xs[b][0] = xa.x; xs[b][1] = xa.y; xs[b][2] = xa.z; xs[b][3] = xa.w;
        xs[b][4] = xv.x; xs[b][5] = xv.y; xs[b][6] = xv.z; xs[b][7] = xv.w;
    }
    float2 acc[NB];
#pragma unroll
    for (int b = 0; b < NB; ++b) { acc[b].x = 0.f; acc[b].y = 0.f; }
    const float* wq = Wc + (size_t)r * (CIN * COUT) + j * 2;
#pragma unroll
    for (int i = 0; i < CIN; ++i) {
        float2 w = *(const float2*)(wq + i * COUT);
#pragma unroll
        for (int b = 0; b < NB; ++b) {
            acc[b].x = fmaf(xs[b][i], w.x, acc[b].x);
            acc[b].y = fmaf(xs[b][i], w.y, acc[b].y);
        }
    }
    const unsigned base = swzu(2u * (unsigned)r + (unsigned)(j >> 2)) * 4u + (unsigned)(j & 3);
#pragma unroll
    for (int b = 0; b < NB; ++b)
        prLDS[b * PLANE + base] = pack_bf16(acc[b].x, acc[b].y);
}

// Per-route iteration body: priors in registers (qa,qb), Vt = V*log2e in LDS.
__device__ __forceinline__ void routeBody(const U4& qa, const U4& qb, int it,
                                          const float* Vt, float* s16, float& se) {
    float e;
    if (it > 0) {
        float d0 = 0.f, d1 = 0.f;   // two chains -> halved dep latency
#pragma unroll
        for (int q = 0; q < 4; ++q) {
            d0 = fmaf(blo(qa.u[q]), Vt[2 * q],     d0);
            d1 = fmaf(bhi(qa.u[q]), Vt[2 * q + 1], d1);
            d0 = fmaf(blo(qb.u[q]), Vt[8 + 2 * q], d0);
            d1 = fmaf(bhi(qb.u[q]), Vt[9 + 2 * q], d1);
        }
        e = exp2f(d0 + d1);   // Vt pre-scaled by log2e -> raw v_exp_f32
    } else {
        e = 1.f;               // iter 0: softmax of zeros
    }
    se += e;
#pragma unroll
    for (int q = 0; q < 4; ++q) {
        s16[2 * q]     = fmaf(e, blo(qa.u[q]), s16[2 * q]);
        s16[2 * q + 1] = fmaf(e, bhi(qa.u[q]), s16[2 * q + 1]);
        s16[8 + 2 * q] = fmaf(e, blo(qb.u[q]), s16[8 + 2 * q]);
        s16[9 + 2 * q] = fmaf(e, bhi(qb.u[q]), s16[9 + 2 * q]);
    }
}

__global__ __launch_bounds__(T) void caps_routing(const float* __restrict__ x,
                                                  const float* __restrict__ W,
                                                  float* __restrict__ out) {
    __shared__ unsigned prLDS[NB * PLANE];          // 73728 B: priors bf16x2, swizzled
    __shared__ float sred[NWAVE][20];               // [wave][comp 0..15, 16=sumExp]
    __shared__ __align__(16) float VLDS[NB][COUT];  // cumulative output * log2e

    const int tid  = threadIdx.x;
    const int lane = tid & 63;
    const int wv   = tid >> 6;

    // XCD-aware swizzle: contiguous widx per XCD -> <=2 capsules -> W L2-resident
    int g    = blockIdx.x;
    int widx = (g & 7) * (NBLK / 8) + (g >> 3);   // bijective, 1280 % 8 == 0
    int c    = widx >> 7;                          // / (BATCH/NB = 128)
    int b0   = (widx & 127) * NB;

    const float* Wc = W + (size_t)c * (NROUTE * CIN * COUT);
    const float* xb = x + (size_t)b0 * XPLANE;

    // ---------------- Phase A: 9216 units = exactly 12 passes ---------------
#pragma unroll 1
    for (int pass = 0; pass < (NROUTE * 8) / T; ++pass) {
        phaseA_unit(pass * T + tid, Wc, xb, prLDS);
    }
    __syncthreads();

    // ---------------- Phase B: priors -> registers, 3 iterations ------------
    // 1152 = 384*3: waves 0-5 own b=0, waves 6-11 own b=1; thread owns routes
    // t384 + {0,384,768} -- loaded ONCE into 6 uint4 (24 VGPR), zero LDS
    // prior-reads inside the iteration loop.
    const int bb   = (tid >= 384) ? 1 : 0;
    const int t384 = tid - 384 * bb;
    const unsigned pbase = (unsigned)bb * PLANE;
    const int comp = ((lane & 1) << 3) | ((lane & 2) << 1) | ((lane & 4) >> 1) | ((lane & 8) >> 3);

    U4 qa0, qb0, qa1, qb1, qa2, qb2;
    {
        const unsigned r0 = (unsigned)t384;
        const unsigned r1 = (unsigned)t384 + 384u;
        const unsigned r2 = (unsigned)t384 + 768u;
        qa0.v = *(const uint4*)&prLDS[pbase + swzu(2u * r0) * 4u];
        qb0.v = *(const uint4*)&prLDS[pbase + swzu(2u * r0 + 1u) * 4u];
        qa1.v = *(const uint4*)&prLDS[pbase + swzu(2u * r1) * 4u];
        qb1.v = *(const uint4*)&prLDS[pbase + swzu(2u * r1 + 1u) * 4u];
        qa2.v = *(const uint4*)&prLDS[pbase + swzu(2u * r2) * 4u];
        qb2.v = *(const uint4*)&prLDS[pbase + swzu(2u * r2 + 1u) * 4u];
    }

#pragma unroll 1
    for (int it = 0; it < 3; ++it) {
        float s16[COUT];
        float se = 0.f;
#pragma unroll
        for (int o = 0; o < COUT; ++o) s16[o] = 0.f;

        const float* Vt = &VLDS[bb][0];
        routeBody(qa0, qb0, it, Vt, s16, se);
        routeBody(qa1, qb1, it, Vt, s16, se);
        routeBody(qa2, qb2, it, Vt, s16, se);

        const float sv  = wave_sum16(s16, lane);
        const float sev = wave_sum(se);
        if (lane < 16) sred[wv][comp] = sv;
        if (lane == 0) sred[wv][16]   = sev;
        __syncthreads();

        if (tid < NB * COUT) {          // 32 threads: reduce 6 waves/b + squash
            const int b = tid >> 4, o = tid & 15;
            float S = 0.f, SE = 0.f;
#pragma unroll
            for (int w = 0; w < 6; ++w) {
                S  += sred[b * 6 + w][o];
                SE += sred[b * 6 + w][16];
            }
            const float tt = S / SE;
            float pq = tt * tt;
            pq += __shfl_xor(pq, 1); pq += __shfl_xor(pq, 2);
            pq += __shfl_xor(pq, 4); pq += __shfl_xor(pq, 8);   // |s|^2 per 16-group
            const float scale = pq / ((1.f + pq) * sqrtf(pq));
            const float val = tt * scale;
            if (it == 2) {
                out[((size_t)c * BATCH + b0 + b) * COUT + o] = val;
            } else {
                const float vt = val * LOG2E;
                VLDS[b][o] = (it == 0) ? vt : (VLDS[b][o] + vt);  // cumulative V*log2e
            }
        }
        __syncthreads();
    }
}

extern "C" void kernel_launch(void* const* d_in, const int* in_sizes, int n_in,
                              void* d_out, int out_size, void* d_ws, size_t ws_size,
                              hipStream_t stream) {
    const float* x = (const float*)d_in[0];
    const float* w = (const float*)d_in[1];
    float* out = (float*)d_out;
    hipLaunchKernelGGL(caps_routing, dim3(NBLK), dim3(T), 0, stream, x, w, out);
}

// Round 14
// 77.895 us; speedup vs baseline: 1.2646x; 1.2646x over previous
//
#include <hip/hip_runtime.h>
#include <cstddef>

#define NCAPS  10
#define BATCH  256
#define NROUTE 1152
#define CIN    8
#define COUT   16
#define T      512           // 8 waves; LDS ~75KB -> 2 blocks/CU
#define NB     2             // batch elements per block
#define NWAVE  (T / 64)
#define NBLK   (NCAPS * (BATCH / NB))   // 1280 blocks = 5 per CU
#define PLANE  (NROUTE * 8)             // u32 (bf16x2) per b-plane = 9216
#define XPLANE (NROUTE * CIN)           // floats per x b-plane = 9216
#define LOG2E  1.4426950408889634f

// bijective 16B-unit swizzle (validated rounds 5-13): conflict-minimal ds_read
__device__ __forceinline__ unsigned swzu(unsigned unit) { return unit ^ ((unit >> 3) & 3u); }

// pack two fp32 -> bf16x2 (RNE), low16 = a
__device__ __forceinline__ unsigned pack_bf16(float a, float b) {
    unsigned ua = __float_as_uint(a); ua += 0x7fffu + ((ua >> 16) & 1u);
    unsigned ub = __float_as_uint(b); ub += 0x7fffu + ((ub >> 16) & 1u);
    return (ua >> 16) | (ub & 0xffff0000u);
}
__device__ __forceinline__ float blo(unsigned u) { return __uint_as_float(u << 16); }
__device__ __forceinline__ float bhi(unsigned u) { return __uint_as_float(u & 0xffff0000u); }

__device__ __forceinline__ float wave_sum(float v) {
    v += __shfl_xor(v, 1);  v += __shfl_xor(v, 2);  v += __shfl_xor(v, 4);
    v += __shfl_xor(v, 8);  v += __shfl_xor(v, 16); v += __shfl_xor(v, 32);
    return v;
}

// Component-splitting butterfly: reduces s[0..15] over 64 lanes. Lane L (L<16)
// ends with the wave total of comp(L)=((L&1)<<3)|((L&2)<<1)|((L&4)>>1)|((L&8)>>3).
__device__ __forceinline__ float wave_sum16(float* s, int lane) {
#pragma unroll
    for (int j = 0; j < 8; ++j) {
        float snd = (lane & 1) ? s[j] : s[j + 8];
        float r = __shfl_xor(snd, 1);
        s[j] = ((lane & 1) ? s[j + 8] : s[j]) + r;
    }
#pragma unroll
    for (int j = 0; j < 4; ++j) {
        float snd = (lane & 2) ? s[j] : s[j + 4];
        float r = __shfl_xor(snd, 2);
        s[j] = ((lane & 2) ? s[j + 4] : s[j]) + r;
    }
#pragma unroll
    for (int j = 0; j < 2; ++j) {
        float snd = (lane & 4) ? s[j] : s[j + 2];
        float r = __shfl_xor(snd, 4);
        s[j] = ((lane & 4) ? s[j + 2] : s[j]) + r;
    }
    {
        float snd = (lane & 8) ? s[0] : s[1];
        float r = __shfl_xor(snd, 8);
        s[0] = ((lane & 8) ? s[1] : s[0]) + r;
    }
    s[0] += __shfl_xor(s[0], 16);
    s[0] += __shfl_xor(s[0], 32);
    return s[0];
}

union U4 { uint4 v; unsigned u[4]; };
union U2 { uint2 v; unsigned u[2]; };

// Phase-A quad unit (R10-validated at NB=2): route r=u>>2, out-quad j4=u&3.
__device__ __forceinline__ void phaseA_unit(int u, const float* __restrict__ Wc,
                                            const float* __restrict__ xb,
                                            unsigned* prLDS) {
    const int r  = u >> 2;
    const int j4 = u & 3;
    float xs[NB][CIN];
#pragma unroll
    for (int b = 0; b < NB; ++b) {
        const float4* xq = (const float4*)(xb + (size_t)b * XPLANE + r * CIN);
        float4 xa = xq[0], xv = xq[1];      // 4-lane broadcast
        xs[b][0] = xa.x; xs[b][1] = xa.y; xs[b][2] = xa.z; xs[b][3] = xa.w;
        xs[b][4] = xv.x; xs[b][5] = xv.y; xs[b][6] = xv.z; xs[b][7] = xv.w;
    }
    float4 acc[NB];
#pragma unroll
    for (int b = 0; b < NB; ++b) acc[b] = make_float4(0.f, 0.f, 0.f, 0.f);
    const float* wq = Wc + (size_t)r * (CIN * COUT) + j4 * 4;
#pragma unroll
    for (int i = 0; i < CIN; ++i) {
        float4 w = *(const float4*)(wq + i * COUT);
#pragma unroll
        for (int b = 0; b < NB; ++b) {
            acc[b].x = fmaf(xs[b][i], w.x, acc[b].x);
            acc[b].y = fmaf(xs[b][i], w.y, acc[b].y);
            acc[b].z = fmaf(xs[b][i], w.z, acc[b].z);
            acc[b].w = fmaf(xs[b][i], w.w, acc[b].w);
        }
    }
    const unsigned base = swzu(2u * (unsigned)r + (unsigned)(j4 >> 1)) * 4u
                        + (unsigned)(j4 & 1) * 2u;
#pragma unroll
    for (int b = 0; b < NB; ++b) {
        U2 q;
        q.u[0] = pack_bf16(acc[b].x, acc[b].y);
        q.u[1] = pack_bf16(acc[b].z, acc[b].w);
        *(uint2*)&prLDS[b * PLANE + base] = q.v;
    }
}

__global__ __launch_bounds__(T) void caps_routing(const float* __restrict__ x,
                                                  const float* __restrict__ W,
                                                  float* __restrict__ out) {
    __shared__ unsigned prLDS[NB * PLANE];   // 73728 B: priors bf16x2, swizzled
    __shared__ float sred[2][NWAVE][20];     // parity-double-buffered: 1 barrier/iter

    const int tid  = threadIdx.x;
    const int lane = tid & 63;
    const int wv   = tid >> 6;

    // XCD-aware swizzle: contiguous widx per XCD -> <=2 capsules -> W L2-resident
    int g    = blockIdx.x;
    int widx = (g & 7) * (NBLK / 8) + (g >> 3);   // bijective, 1280 % 8 == 0
    int c    = widx >> 7;                          // / (BATCH/NB = 128)
    int b0   = (widx & 127) * NB;

    const float* Wc = W + (size_t)c * (NROUTE * CIN * COUT);
    const float* xb = x + (size_t)b0 * XPLANE;

    // ---------------- Phase A: 4608 quad units = exactly 9 passes -----------
#pragma unroll 1
    for (int pass = 0; pass < (NROUTE * 4) / T; ++pass) {
        phaseA_unit(pass * T + tid, Wc, xb, prLDS);
    }
    __syncthreads();

    // ---------------- Phase B: b-split, V in registers, 1 barrier/iter ------
    // 256 threads per b (bb = tid>>8): 4 main routes + half-row leftover.
    // V (cumulative output * log2e) computed REDUNDANTLY by every thread from
    // broadcast sred reads -> no serialized squash section, no V LDS round-trip.
    const int bb   = tid >> 8;
    const int t256 = tid & 255;
    const int h    = t256 & 1;            // leftover half
    const int r2   = 1024 + (t256 >> 1);  // leftover route
    const unsigned pbase = (unsigned)bb * PLANE;
    const int comp = ((lane & 1) << 3) | ((lane & 2) << 1) | ((lane & 4) >> 1) | ((lane & 8) >> 3);

    float V[COUT];
#pragma unroll
    for (int o = 0; o < COUT; ++o) V[o] = 0.f;

#pragma unroll 1
    for (int it = 0; it < 3; ++it) {
        float s16[COUT];
        float se = 0.f;
#pragma unroll
        for (int o = 0; o < COUT; ++o) s16[o] = 0.f;

        // 4 main routes (independent bodies -> ILP)
#pragma unroll
        for (int k = 0; k < 4; ++k) {
            const int r = (k << 8) + t256;
            U4 qa, qb;
            qa.v = *(const uint4*)&prLDS[pbase + swzu(2u * (unsigned)r) * 4u];
            qb.v = *(const uint4*)&prLDS[pbase + swzu(2u * (unsigned)r + 1u) * 4u];
            float e;
            if (it > 0) {
                float d0 = 0.f, d1 = 0.f;   // two chains -> halved dep latency
#pragma unroll
                for (int q = 0; q < 4; ++q) {
                    d0 = fmaf(blo(qa.u[q]), V[2 * q],     d0);
                    d1 = fmaf(bhi(qa.u[q]), V[2 * q + 1], d1);
                    d0 = fmaf(blo(qb.u[q]), V[8 + 2 * q], d0);
                    d1 = fmaf(bhi(qb.u[q]), V[9 + 2 * q], d1);
                }
                e = exp2f(d0 + d1);   // V pre-scaled by log2e -> raw v_exp_f32
            } else {
                e = 1.f;               // iter 0: softmax of zeros
            }
            se += e;
#pragma unroll
            for (int q = 0; q < 4; ++q) {
                s16[2 * q]     = fmaf(e, blo(qa.u[q]), s16[2 * q]);
                s16[2 * q + 1] = fmaf(e, bhi(qa.u[q]), s16[2 * q + 1]);
                s16[8 + 2 * q] = fmaf(e, blo(qb.u[q]), s16[8 + 2 * q]);
                s16[9 + 2 * q] = fmaf(e, bhi(qb.u[q]), s16[9 + 2 * q]);
            }
        }

        // leftover route: half-row (8 outs), pair partner = lane^1 (same wave)
        {
            U4 q;
            q.v = *(const uint4*)&prLDS[pbase + swzu(2u * (unsigned)r2 + (unsigned)h) * 4u];
            float pl[8];
#pragma unroll
            for (int u = 0; u < 4; ++u) { pl[2 * u] = blo(q.u[u]); pl[2 * u + 1] = bhi(q.u[u]); }
            float e2;
            if (it > 0) {
                float d2 = 0.f;
#pragma unroll
                for (int j = 0; j < 8; ++j) d2 = fmaf(pl[j], V[h * 8 + j], d2);
                d2 += __shfl_xor(d2, 1);    // combine halves
                e2 = exp2f(d2);
            } else {
                e2 = 1.f;
            }
            se += 0.5f * e2;                // 2 lanes each add half of exp -> exact
#pragma unroll
            for (int j = 0; j < 8; ++j) {
                const float add = e2 * pl[j];
                s16[j]     += (h == 0) ? add : 0.f;
                s16[8 + j] += (h == 1) ? add : 0.f;
            }
        }

        const float sv  = wave_sum16(s16, lane);
        const float sev = wave_sum(se);
        float (*sb)[20] = sred[it & 1];     // parity buffer: no WAR across iters
        if (lane < 16) sb[wv][comp] = sv;
        if (lane == 0) sb[wv][16]   = sev;
        __syncthreads();                     // the ONLY barrier this iteration

        if (it < 2) {
            // redundant finish: every thread reduces its b's 4 rows (broadcast)
            float Ssum[COUT];
            float SE = 0.f;
#pragma unroll
            for (int o = 0; o < COUT; ++o) Ssum[o] = 0.f;
#pragma unroll
            for (int w = 0; w < 4; ++w) {
                const float* rp = &sb[bb * 4 + w][0];
                float4 a0 = *(const float4*)&rp[0];
                float4 a1 = *(const float4*)&rp[4];
                float4 a2 = *(const float4*)&rp[8];
                float4 a3 = *(const float4*)&rp[12];
                Ssum[0] += a0.x; Ssum[1] += a0.y; Ssum[2]  += a0.z; Ssum[3]  += a0.w;
                Ssum[4] += a1.x; Ssum[5] += a1.y; Ssum[6]  += a1.z; Ssum[7]  += a1.w;
                Ssum[8] += a2.x; Ssum[9] += a2.y; Ssum[10] += a2.z; Ssum[11] += a2.w;
                Ssum[12] += a3.x; Ssum[13] += a3.y; Ssum[14] += a3.z; Ssum[15] += a3.w;
                SE += rp[16];
            }
            // squash via q2 = sum(S^2): pq = q2/SE^2; no tt array needed
            const float inv = 1.f / SE;
            float q2 = 0.f;
#pragma unroll
            for (int o = 0; o < COUT; ++o) q2 = fmaf(Ssum[o], Ssum[o], q2);
            const float pq = q2 * inv * inv;
            const float factor = inv * (pq / ((1.f + pq) * sqrtf(pq))) * LOG2E;
#pragma unroll
            for (int o = 0; o < COUT; ++o) V[o] = fmaf(Ssum[o], factor, V[o]);
        } else {
            // it==2: 32 threads produce outputs (R7-proven path)
            if (tid < NB * COUT) {
                const int b = tid >> 4, o = tid & 15;
                float S = 0.f, SE = 0.f;
#pragma unroll
                for (int w = 0; w < 4; ++w) {
                    S  += sb[b * 4 + w][o];
                    SE += sb[b * 4 + w][16];
                }
                const float tt = S / SE;
                float pq = tt * tt;
                pq += __shfl_xor(pq, 1); pq += __shfl_xor(pq, 2);
                pq += __shfl_xor(pq, 4); pq += __shfl_xor(pq, 8);
                const float scale = pq / ((1.f + pq) * sqrtf(pq));
                out[((size_t)c * BATCH + b0 + b) * COUT + o] = tt * scale;
            }
        }
    }
}

extern "C" void kernel_launch(void* const* d_in, const int* in_sizes, int n_in,
                              void* d_out, int out_size, void* d_ws, size_t ws_size,
                              hipStream_t stream) {
    const float* x = (const float*)d_in[0];
    const float* w = (const float*)d_in[1];
    float* out = (float*)d_out;
    hipLaunchKernelGGL(caps_routing, dim3(NBLK), dim3(T), 0, stream, x, w, out);
}